// Round 7
// baseline (102.405 us; speedup 1.0000x reference)
//
#include <hip/hip_runtime.h>
#include <stdint.h>

// CoordinateDensification: neighbor-expand (27 offsets, stride*[-1,0,1]^3) then
// unique rows sorted lexicographically, padded with INT32_MAX to N*27 rows.
//
// Bitmap layout (slice-major, lexicographic): slice B = biased c0' in [0, R),
// within-slice bit = c1'*R + c2', word = B*W + bit/32, W = ceil(R*R/32).
//
// Fast path, 5 launches (no global atomics, no bitmap pre-zero):
//   1. hist     : per-block c0 histograms (LDS atomics)
//   2. scan_off : class starts + per-block offsets (1 block)
//   3. sort     : counting-sort coords -> packed (c1,c2) ushort entries
//   4. mark_lds : per-slice LDS bitmap, LDS atomicOr, plain-store flush
//                 + per-256-word group popcount sums (wave reduce)
//   5. scatter_fill: each block reduces gs[0..id) for its base (L2-hot),
//                 prefix-scans popcounts in LDS, then emits output row r by
//                 binary-search + k-th-bit-select -> fully coalesced
//                 nontemporal int4 stores; spare blocks fill the padding
//                 tail [cnt, N*27) with INT32_MAX (also nontemporal).
// Fallback (small ws): round-1-style global-atomic mark pipeline.

typedef int v4i __attribute__((ext_vector_type(4)));

static constexpr int MAXSTRIDE  = 8;
static constexpr int MAXR       = 256 + 2 * MAXSTRIDE;      // 272
static constexpr int MAXSLICES  = MAXR;                     // 272
static constexpr int MAXW       = (MAXR * MAXR + 31) / 32;  // 2312 words/slice
static constexpr int MAXGPS     = (MAXW + 255) / 256;       // 10 groups/slice
static constexpr int MAXWORDS   = MAXSLICES * MAXW;         // 628,864 words
static constexpr int FILLV      = 0x7FFFFFFF;
static constexpr int SORTB      = 128;
static constexpr int FILLBLOCKS = 1024;
static constexpr int SCGRID     = MAXSLICES * MAXGPS + FILLBLOCKS;  // 3744
// fallback scan geometry
static constexpr int WPB        = 1024;
static constexpr int NBSCAN     = (MAXWORDS + WPB - 1) / WPB;       // 615

// ws layout (uint32_t words):
static constexpr int CNT   = 0;                      // unique count (fallback)
static constexpr int BSOFF = 16;                     // fallback block sums [615]
static constexpr int GSOFF = 1024;                   // group sums [<=2720]
static constexpr int BMOFF = 4096;                   // bitmap [MAXWORDS]
static constexpr int HOFF  = BMOFF + MAXWORDS;       // hist SORTBx256
static constexpr int OOFF  = HOFF + SORTB * 256;     // per-block class offsets
static constexpr int CSOFF = OOFF + SORTB * 256;     // class starts [257]
static constexpr int EOFF  = CSOFF + 512;            // packed entries (ushort)

// ---------------- counting sort ------------------------------------------
__global__ void hist_kernel(const int4* __restrict__ coords, uint32_t* __restrict__ ws, int n) {
    __shared__ uint32_t h[256];
    const int t = threadIdx.x, b = blockIdx.x;
    h[t] = 0;
    __syncthreads();
    const int chunk = (n + gridDim.x - 1) / gridDim.x;
    const int start = b * chunk;
    const int end = min(n, start + chunk);
    for (int i = start + t; i < end; i += 256)
        atomicAdd(&h[coords[i].x], 1u);
    __syncthreads();
    ws[HOFF + b * 256 + t] = h[t];
}

__global__ void scan_off_kernel(uint32_t* __restrict__ ws) {
    __shared__ uint32_t sh[256];
    const int c = threadIdx.x;
    const uint32_t* H = ws + HOFF;
    uint32_t* O = ws + OOFF;
    uint32_t* CS = ws + CSOFF;
    uint32_t run = 0;
    for (int b = 0; b < SORTB; ++b) {
        O[b * 256 + c] = run;
        run += H[b * 256 + c];
    }
    sh[c] = run;
    __syncthreads();
    for (int st = 1; st < 256; st <<= 1) {
        uint32_t x = sh[c];
        if (c >= st) x += sh[c - st];
        __syncthreads();
        sh[c] = x;
        __syncthreads();
    }
    CS[c] = sh[c] - run;
    if (c == 255) CS[256] = sh[255];
}

__global__ void sort_kernel(const int4* __restrict__ coords, uint32_t* __restrict__ ws, int n) {
    __shared__ uint32_t cnt[256];
    __shared__ uint32_t obase[256];
    const int t = threadIdx.x, b = blockIdx.x;
    cnt[t] = 0;
    obase[t] = ws[OOFF + b * 256 + t] + ws[CSOFF + t];
    __syncthreads();
    uint16_t* entries = (uint16_t*)(ws + EOFF);
    const int chunk = (n + gridDim.x - 1) / gridDim.x;
    const int start = b * chunk;
    const int end = min(n, start + chunk);
    for (int i = start + t; i < end; i += 256) {
        const int4 c = coords[i];
        const uint32_t r = atomicAdd(&cnt[c.x], 1u);
        entries[obase[c.x] + r] = (uint16_t)((c.y << 8) | c.z);
    }
}

// ---------------- fast mark: LDS bitmap + flush + group sums -------------
__global__ __launch_bounds__(1024) void mark_lds_kernel(uint32_t* __restrict__ ws,
                                                        const int* __restrict__ dstride) {
    __shared__ uint32_t bm[MAXW];
    const int B = blockIdx.x, t = threadIdx.x;
    const int s = dstride[0];
    const int R = 256 + 2 * s;
    const int W = (R * R + 31) >> 5;
    const int GPS = (W + 255) >> 8;
    if (B >= R) return;                       // uniform per block
    for (int w = t; w < MAXW; w += 1024) bm[w] = 0;
    __syncthreads();
    const uint32_t* CS = ws + CSOFF;
    const uint16_t* entries = (const uint16_t*)(ws + EOFF);
#pragma unroll
    for (int k = 0; k < 3; ++k) {
        const int c0 = B - k * s;             // class whose iz=k neighbor is slice B
        if (c0 < 0 || c0 > 255) continue;
        const uint32_t st = CS[c0], en = CS[c0 + 1];
        for (uint32_t i = st + t; i < en; i += 1024) {
            const uint32_t e = entries[i];
            const int c1 = e >> 8, c2 = e & 255;
#pragma unroll
            for (int iy = 0; iy < 3; ++iy) {
                const int b0 = (c1 + iy * s) * R + c2;   // ix = 0 (biased)
                const int w0 = b0 >> 5, off = b0 & 31;
                if (off + 2 * s < 32) {
                    atomicOr(&bm[w0], (1u << off) | (1u << (off + s)) | (1u << (off + 2 * s)));
                } else {
#pragma unroll
                    for (int ix = 0; ix < 3; ++ix) {
                        const int bb = b0 + ix * s;
                        atomicOr(&bm[bb >> 5], 1u << (bb & 31));
                    }
                }
            }
        }
    }
    __syncthreads();
    // flush: every word written (zeros included) -> no global pre-zero needed
    uint32_t* g = ws + BMOFF + (size_t)B * W;
    for (int w = t; w < W; w += 1024) g[w] = bm[w];
    // group sums: wave wv handles words [wv*256, wv*256+256) of this slice
    const int wv = t >> 6, ln = t & 63;
    if (wv < GPS) {
        uint32_t s4 = 0;
        const int w0 = wv * 256 + ln * 4;
#pragma unroll
        for (int j = 0; j < 4; ++j)
            if (w0 + j < W) s4 += __popc(bm[w0 + j]);
#pragma unroll
        for (int off = 32; off > 0; off >>= 1) s4 += __shfl_down(s4, off);
        if (ln == 0) ws[GSOFF + B * GPS + wv] = s4;
    }
}

// ---------------- scatter + tail fill (fused, coalesced nt stores) -------
__global__ __launch_bounds__(256) void scatter_fill_kernel(const uint32_t* __restrict__ ws,
                                                           const int* __restrict__ dstride,
                                                           int* __restrict__ out, int n4) {
    const int s = dstride[0];
    const int R = 256 + 2 * s;
    const int W = (R * R + 31) >> 5;
    const int GPS = (W + 255) >> 8;
    const int NG = R * GPS;
    const int id = blockIdx.x, t = threadIdx.x;
    const uint32_t* gs = ws + GSOFF;
    v4i* out4 = reinterpret_cast<v4i*>(out);

    __shared__ uint32_t sh[256];
    __shared__ uint32_t ps[257];
    __shared__ uint32_t wds[256];

    if (id >= NG) {                            // tail-fill role (block-uniform)
        uint32_t acc = 0;
        for (int j = t; j < NG; j += 256) acc += gs[j];
        sh[t] = acc;
        __syncthreads();
        for (int st = 128; st > 0; st >>= 1) {
            if (t < st) sh[t] += sh[t + st];
            __syncthreads();
        }
        const uint32_t cnt = sh[0];            // total unique rows
        const uint32_t fb = (uint32_t)(id - NG);
        const uint32_t FB = (uint32_t)(gridDim.x - NG);
        const v4i f = {FILLV, FILLV, FILLV, FILLV};
        for (uint32_t i = cnt + fb * 256u + (uint32_t)t; i < (uint32_t)n4; i += FB * 256u)
            __builtin_nontemporal_store(f, out4 + i);
        return;
    }

    const int B = id / GPS;
    const int g = id - B * GPS;
    const int widx = g * 256 + t;              // word within slice
    const uint32_t wd = (widx < W) ? ws[BMOFF + (size_t)B * W + widx] : 0u;
    wds[t] = wd;
    const uint32_t pc = __popc(wd);

    // block output base = sum of gs[0..id)  (gs is tiny & L2-hot)
    uint32_t acc = 0;
    for (int j = t; j < id; j += 256) acc += gs[j];
    sh[t] = acc;
    __syncthreads();
    for (int st = 128; st > 0; st >>= 1) {
        if (t < st) sh[t] += sh[t + st];
        __syncthreads();
    }
    const uint32_t gbase = sh[0];
    __syncthreads();

    // inclusive scan of popcounts -> ps[w] (exclusive at index w)
    sh[t] = pc;
    __syncthreads();
    for (int st = 1; st < 256; st <<= 1) {
        uint32_t x = sh[t];
        if (t >= st) x += sh[t - st];
        __syncthreads();
        sh[t] = x;
        __syncthreads();
    }
    ps[t + 1] = sh[t];
    if (t == 0) ps[0] = 0;
    __syncthreads();
    const uint32_t total = ps[256];

    // row r of this block -> binary search word, select k-th set bit, decode
    for (uint32_t r = t; r < total; r += 256) {
        int lo = 0, hi = 255;
        while (lo < hi) {
            const int mid = (lo + hi + 1) >> 1;
            if (ps[mid] <= r) lo = mid; else hi = mid - 1;
        }
        const int w = lo;
        uint32_t k = r - ps[w];
        uint32_t m = wds[w];
        while (k--) m &= m - 1;
        const int bit = __ffs(m) - 1;
        const int inbit = ((g * 256 + w) << 5) + bit;
        const int c1 = inbit / R;
        const int c2 = inbit - c1 * R;
        const v4i val = {B - s, c1 - s, c2 - s, 0};
        __builtin_nontemporal_store(val, out4 + gbase + r);
    }
}

// ================= fallback path (small ws): global-atomic mark ==========
__global__ void zero_ws_kernel(uint32_t* __restrict__ ws, int nwords) {
    int i = blockIdx.x * blockDim.x + threadIdx.x;
    if (i < nwords) ws[i] = 0u;
}

__global__ void mark_global_kernel(const int4* __restrict__ coords,
                                   const int* __restrict__ dstride,
                                   uint32_t* __restrict__ bitmap, int n) {
    int i = blockIdx.x * blockDim.x + threadIdx.x;
    if (i >= n) return;
    const int s = dstride[0];
    const int R = 256 + 2 * s;
    const int W = (R * R + 31) >> 5;
    const int4 c = coords[i];
#pragma unroll
    for (int iz = 0; iz < 3; ++iz) {
        uint32_t* sl = bitmap + (size_t)(c.x + iz * s) * W;
#pragma unroll
        for (int iy = 0; iy < 3; ++iy) {
            const int b0 = (c.y + iy * s) * R + c.z;
            const int w0 = b0 >> 5, off = b0 & 31;
            if (off + 2 * s < 32) {
                atomicOr(sl + w0, (1u << off) | (1u << (off + s)) | (1u << (off + 2 * s)));
            } else {
#pragma unroll
                for (int ix = 0; ix < 3; ++ix) {
                    const int bb = b0 + ix * s;
                    atomicOr(sl + (bb >> 5), 1u << (bb & 31));
                }
            }
        }
    }
}

__global__ void block_sums_kernel(uint32_t* __restrict__ ws) {
    __shared__ uint32_t red[256];
    const uint32_t* bitmap = ws + BMOFF;
    uint32_t* bs = ws + BSOFF;
    const int b = blockIdx.x, t = threadIdx.x;
    const int w = b * WPB + t * 4;
    uint32_t s = 0;
    if (w + 3 < MAXWORDS) {
        const uint4 v = *reinterpret_cast<const uint4*>(bitmap + w);
        s = __popc(v.x) + __popc(v.y) + __popc(v.z) + __popc(v.w);
    } else {
#pragma unroll
        for (int j = 0; j < 4; ++j)
            if (w + j < MAXWORDS) s += __popc(bitmap[w + j]);
    }
    red[t] = s;
    __syncthreads();
    for (int st = 128; st > 0; st >>= 1) {
        if (t < st) red[t] += red[t + st];
        __syncthreads();
    }
    if (t == 0) bs[b] = red[0];
}

__global__ void scan_sums_kernel(uint32_t* __restrict__ ws) {
    __shared__ uint32_t sh[1024];
    const int t = threadIdx.x;
    uint32_t* bs = ws + BSOFF;
    const uint32_t v = (t < NBSCAN) ? bs[t] : 0u;
    sh[t] = v;
    __syncthreads();
    for (int st = 1; st < 1024; st <<= 1) {
        uint32_t x = sh[t];
        if (t >= st) x += sh[t - st];
        __syncthreads();
        sh[t] = x;
        __syncthreads();
    }
    if (t < NBSCAN) bs[t] = sh[t] - v;
    if (t == 0) ws[CNT] = sh[1023];
}

__global__ void fill_tail_gs_kernel(int4* __restrict__ out, const uint32_t* __restrict__ ws, int n4) {
    const uint32_t cnt = ws[CNT];
    const uint32_t stride = gridDim.x * 256u;
    const int4 f = make_int4(FILLV, FILLV, FILLV, FILLV);
    for (uint32_t i = cnt + blockIdx.x * 256u + threadIdx.x; i < (uint32_t)n4; i += stride)
        out[i] = f;
}

__global__ void scatter_fb_kernel(const uint32_t* __restrict__ ws, const int* __restrict__ dstride,
                                  int* __restrict__ out) {
    __shared__ uint32_t sh[256];
    const uint32_t* bitmap = ws + BMOFF;
    const uint32_t* boffs = ws + BSOFF;
    const int b = blockIdx.x, t = threadIdx.x;
    const int s = dstride[0];
    const int R = 256 + 2 * s;
    const int W = (R * R + 31) >> 5;
    const int w = b * WPB + t * 4;
    uint32_t wd[4] = {0u, 0u, 0u, 0u};
    if (w + 3 < MAXWORDS) {
        const uint4 v = *reinterpret_cast<const uint4*>(bitmap + w);
        wd[0] = v.x; wd[1] = v.y; wd[2] = v.z; wd[3] = v.w;
    } else {
#pragma unroll
        for (int j = 0; j < 4; ++j)
            if (w + j < MAXWORDS) wd[j] = bitmap[w + j];
    }
    const uint32_t cnt = __popc(wd[0]) + __popc(wd[1]) + __popc(wd[2]) + __popc(wd[3]);
    sh[t] = cnt;
    __syncthreads();
    for (int st = 1; st < 256; st <<= 1) {
        uint32_t x = sh[t];
        if (t >= st) x += sh[t - st];
        __syncthreads();
        sh[t] = x;
        __syncthreads();
    }
    uint32_t pos = boffs[b] + sh[t] - cnt;
    int4* out4 = reinterpret_cast<int4*>(out);
#pragma unroll
    for (int j = 0; j < 4; ++j) {
        uint32_t m = wd[j];
        if (!m) continue;
        const int wi = w + j;
        const int slice = wi / W;
        const int base = (wi - slice * W) * 32;
        while (m) {
            const int bit = __ffs(m) - 1;
            m &= m - 1;
            const int inbit = base + bit;
            const int c1i = inbit / R;
            const int c2i = inbit - c1i * R;
            out4[pos++] = make_int4(slice - s, c1i - s, c2i - s, 0);
        }
    }
}

extern "C" void kernel_launch(void* const* d_in, const int* in_sizes, int n_in,
                              void* d_out, int out_size, void* d_ws, size_t ws_size,
                              hipStream_t stream) {
    const int4* coords = (const int4*)d_in[0];
    const int* dstride = (const int*)d_in[1];
    int* out = (int*)d_out;
    uint32_t* ws = (uint32_t*)d_ws;
    const int n = in_sizes[0] / 4;      // 500,000 coords
    const int rows4 = out_size / 4;     // 13,500,000 output rows

    const size_t need_fast = ((size_t)EOFF + (size_t)(n + 1) / 2) * 4;  // ~3.8 MB
    const bool fast = ws_size >= need_fast;

    if (fast) {
        hipLaunchKernelGGL(hist_kernel, dim3(SORTB), dim3(256), 0, stream, coords, ws, n);
        hipLaunchKernelGGL(scan_off_kernel, dim3(1), dim3(256), 0, stream, ws);
        hipLaunchKernelGGL(sort_kernel, dim3(SORTB), dim3(256), 0, stream, coords, ws, n);
        hipLaunchKernelGGL(mark_lds_kernel, dim3(MAXSLICES), dim3(1024), 0, stream, ws, dstride);
        hipLaunchKernelGGL(scatter_fill_kernel, dim3(SCGRID), dim3(256), 0, stream,
                           ws, dstride, out, rows4);
    } else {
        const int zeroN = BMOFF + MAXWORDS;
        hipLaunchKernelGGL(zero_ws_kernel, dim3((zeroN + 255) / 256), dim3(256), 0, stream, ws, zeroN);
        hipLaunchKernelGGL(mark_global_kernel, dim3((n + 255) / 256), dim3(256), 0, stream,
                           coords, dstride, ws + BMOFF, n);
        hipLaunchKernelGGL(block_sums_kernel, dim3(NBSCAN), dim3(256), 0, stream, ws);
        hipLaunchKernelGGL(scan_sums_kernel, dim3(1), dim3(1024), 0, stream, ws);
        hipLaunchKernelGGL(fill_tail_gs_kernel, dim3(1024), dim3(256), 0, stream,
                           (int4*)out, ws, rows4);
        hipLaunchKernelGGL(scatter_fb_kernel, dim3(NBSCAN), dim3(256), 0, stream, ws, dstride, out);
    }
}

// Round 8
// 74.584 us; speedup vs baseline: 1.3730x; 1.3730x over previous
//
#include <hip/hip_runtime.h>
#include <stdint.h>

// CoordinateDensification: neighbor-expand (27 offsets, stride*[-1,0,1]^3) then
// unique rows sorted lexicographically, padded with INT32_MAX to N*27 rows.
//
// Bitmap layout (slice-major, lexicographic): slice B = biased c0' in [0, R),
// within-slice bit = c1'*R + c2', word = B*W + bit/32, W = ceil(R*R/32).
//
// Fast path, 6 launches (== round-4 proven 90us structure; single change this
// round: scatter uses row-parallel coalesced stores instead of per-word walk):
//   1. hist       2. scan_off       3. sort (counting-sort by c0)
//   4. mark_lds   (per-slice LDS bitmap + flush + group popcount sums)
//   5. scan_groups (1-block exclusive scan of group sums -> ws[CNT])
//   6. scatter_fill: thread t emits rows r = t + 256*i of its group via
//      binary-search in LDS prefix + branchless k-th-set-bit select ->
//      wave-contiguous plain int4 stores; spare blocks fill the tail.
// Fallback (small ws): round-1-style global-atomic mark pipeline.

static constexpr int MAXSTRIDE  = 8;
static constexpr int MAXR       = 256 + 2 * MAXSTRIDE;      // 272
static constexpr int MAXSLICES  = MAXR;                     // 272
static constexpr int MAXW       = (MAXR * MAXR + 31) / 32;  // 2312 words/slice
static constexpr int MAXGPS     = (MAXW + 255) / 256;       // 10 groups/slice
static constexpr int MAXWORDS   = MAXSLICES * MAXW;         // 628,864 words
static constexpr int FILLV      = 0x7FFFFFFF;
static constexpr int SORTB      = 128;
static constexpr int FILLBLOCKS = 1024;
static constexpr int SCGRID     = MAXSLICES * MAXGPS + FILLBLOCKS;  // 3744
// fallback scan geometry
static constexpr int WPB        = 1024;
static constexpr int NBSCAN     = (MAXWORDS + WPB - 1) / WPB;       // 615

// ws layout (uint32_t words):
static constexpr int CNT   = 0;                      // unique count
static constexpr int BSOFF = 16;                     // fallback block sums [615]
static constexpr int GSOFF = 1024;                   // group sums [<=2720]
static constexpr int BMOFF = 4096;                   // bitmap [MAXWORDS]
static constexpr int HOFF  = BMOFF + MAXWORDS;       // hist SORTBx256
static constexpr int OOFF  = HOFF + SORTB * 256;     // per-block class offsets
static constexpr int CSOFF = OOFF + SORTB * 256;     // class starts [257]
static constexpr int EOFF  = CSOFF + 512;            // packed entries (ushort)

// ---------------- counting sort ------------------------------------------
__global__ void hist_kernel(const int4* __restrict__ coords, uint32_t* __restrict__ ws, int n) {
    __shared__ uint32_t h[256];
    const int t = threadIdx.x, b = blockIdx.x;
    h[t] = 0;
    __syncthreads();
    const int chunk = (n + gridDim.x - 1) / gridDim.x;
    const int start = b * chunk;
    const int end = min(n, start + chunk);
    for (int i = start + t; i < end; i += 256)
        atomicAdd(&h[coords[i].x], 1u);
    __syncthreads();
    ws[HOFF + b * 256 + t] = h[t];
}

__global__ void scan_off_kernel(uint32_t* __restrict__ ws) {
    __shared__ uint32_t sh[256];
    const int c = threadIdx.x;
    const uint32_t* H = ws + HOFF;
    uint32_t* O = ws + OOFF;
    uint32_t* CS = ws + CSOFF;
    uint32_t run = 0;
    for (int b = 0; b < SORTB; ++b) {
        O[b * 256 + c] = run;
        run += H[b * 256 + c];
    }
    sh[c] = run;
    __syncthreads();
    for (int st = 1; st < 256; st <<= 1) {
        uint32_t x = sh[c];
        if (c >= st) x += sh[c - st];
        __syncthreads();
        sh[c] = x;
        __syncthreads();
    }
    CS[c] = sh[c] - run;
    if (c == 255) CS[256] = sh[255];
}

__global__ void sort_kernel(const int4* __restrict__ coords, uint32_t* __restrict__ ws, int n) {
    __shared__ uint32_t cnt[256];
    __shared__ uint32_t obase[256];
    const int t = threadIdx.x, b = blockIdx.x;
    cnt[t] = 0;
    obase[t] = ws[OOFF + b * 256 + t] + ws[CSOFF + t];
    __syncthreads();
    uint16_t* entries = (uint16_t*)(ws + EOFF);
    const int chunk = (n + gridDim.x - 1) / gridDim.x;
    const int start = b * chunk;
    const int end = min(n, start + chunk);
    for (int i = start + t; i < end; i += 256) {
        const int4 c = coords[i];
        const uint32_t r = atomicAdd(&cnt[c.x], 1u);
        entries[obase[c.x] + r] = (uint16_t)((c.y << 8) | c.z);
    }
}

// ---------------- fast mark: LDS bitmap + flush + group sums -------------
__global__ __launch_bounds__(1024) void mark_lds_kernel(uint32_t* __restrict__ ws,
                                                        const int* __restrict__ dstride) {
    __shared__ uint32_t bm[MAXW];
    const int B = blockIdx.x, t = threadIdx.x;
    const int s = dstride[0];
    const int R = 256 + 2 * s;
    const int W = (R * R + 31) >> 5;
    const int GPS = (W + 255) >> 8;
    if (B >= R) return;                       // uniform per block
    for (int w = t; w < MAXW; w += 1024) bm[w] = 0;
    __syncthreads();
    const uint32_t* CS = ws + CSOFF;
    const uint16_t* entries = (const uint16_t*)(ws + EOFF);
#pragma unroll
    for (int k = 0; k < 3; ++k) {
        const int c0 = B - k * s;             // class whose iz=k neighbor is slice B
        if (c0 < 0 || c0 > 255) continue;
        const uint32_t st = CS[c0], en = CS[c0 + 1];
        for (uint32_t i = st + t; i < en; i += 1024) {
            const uint32_t e = entries[i];
            const int c1 = e >> 8, c2 = e & 255;
#pragma unroll
            for (int iy = 0; iy < 3; ++iy) {
                const int b0 = (c1 + iy * s) * R + c2;   // ix = 0 (biased)
                const int w0 = b0 >> 5, off = b0 & 31;
                if (off + 2 * s < 32) {
                    atomicOr(&bm[w0], (1u << off) | (1u << (off + s)) | (1u << (off + 2 * s)));
                } else {
#pragma unroll
                    for (int ix = 0; ix < 3; ++ix) {
                        const int bb = b0 + ix * s;
                        atomicOr(&bm[bb >> 5], 1u << (bb & 31));
                    }
                }
            }
        }
    }
    __syncthreads();
    // flush: every word written (zeros included) -> no global pre-zero needed
    uint32_t* g = ws + BMOFF + (size_t)B * W;
    for (int w = t; w < W; w += 1024) g[w] = bm[w];
    // group sums: wave wv handles words [wv*256, wv*256+256) of this slice
    const int wv = t >> 6, ln = t & 63;
    if (wv < GPS) {
        uint32_t s4 = 0;
        const int w0 = wv * 256 + ln * 4;
#pragma unroll
        for (int j = 0; j < 4; ++j)
            if (w0 + j < W) s4 += __popc(bm[w0 + j]);
#pragma unroll
        for (int off = 32; off > 0; off >>= 1) s4 += __shfl_down(s4, off);
        if (ln == 0) ws[GSOFF + B * GPS + wv] = s4;
    }
}

// ---------------- scan of group sums (1 block) ---------------------------
__global__ __launch_bounds__(1024) void scan_groups_kernel(uint32_t* __restrict__ ws,
                                                           const int* __restrict__ dstride) {
    __shared__ uint32_t sh[1024];
    const int t = threadIdx.x;
    const int s = dstride[0];
    const int R = 256 + 2 * s;
    const int W = (R * R + 31) >> 5;
    const int GPS = (W + 255) >> 8;
    const int NG = R * GPS;                   // <= 2720 <= 3072
    uint32_t* gs = ws + GSOFF;
    uint32_t v[3];
    uint32_t tot = 0;
    const int base = t * 3;
#pragma unroll
    for (int j = 0; j < 3; ++j) {
        v[j] = (base + j < NG) ? gs[base + j] : 0u;
        tot += v[j];
    }
    sh[t] = tot;
    __syncthreads();
    for (int st = 1; st < 1024; st <<= 1) {
        uint32_t x = sh[t];
        if (t >= st) x += sh[t - st];
        __syncthreads();
        sh[t] = x;
        __syncthreads();
    }
    uint32_t run = sh[t] - tot;               // exclusive prefix of this thread's span
#pragma unroll
    for (int j = 0; j < 3; ++j) {
        if (base + j < NG) gs[base + j] = run;
        run += v[j];
    }
    if (t == 1023) ws[CNT] = sh[1023];
}

// ---------------- scatter + tail fill (fused, coalesced plain stores) ----
__global__ __launch_bounds__(256) void scatter_fill_kernel(const uint32_t* __restrict__ ws,
                                                           const int* __restrict__ dstride,
                                                           int* __restrict__ out, int n4) {
    const int s = dstride[0];
    const int R = 256 + 2 * s;
    const int W = (R * R + 31) >> 5;
    const int GPS = (W + 255) >> 8;
    const int NG = R * GPS;
    const int id = blockIdx.x, t = threadIdx.x;
    int4* out4 = reinterpret_cast<int4*>(out);

    if (id >= NG) {                            // tail-fill role (block-uniform)
        const uint32_t cnt = ws[CNT];
        const uint32_t fb = (uint32_t)(id - NG);
        const uint32_t FB = (uint32_t)(gridDim.x - NG);
        const int4 f = make_int4(FILLV, FILLV, FILLV, FILLV);
        for (uint32_t i = cnt + fb * 256u + (uint32_t)t; i < (uint32_t)n4; i += FB * 256u)
            out4[i] = f;
        return;
    }

    __shared__ uint32_t sh[256];
    __shared__ uint32_t ps[257];
    __shared__ uint32_t wds[256];

    const int B = id / GPS;
    const int g = id - B * GPS;
    const int widx = g * 256 + t;              // word within slice
    const uint32_t wd = (widx < W) ? ws[BMOFF + (size_t)B * W + widx] : 0u;
    wds[t] = wd;
    const uint32_t pc = __popc(wd);

    // inclusive scan of popcounts -> ps[] (ps[w] = exclusive prefix at word w)
    sh[t] = pc;
    __syncthreads();
    for (int st = 1; st < 256; st <<= 1) {
        uint32_t x = sh[t];
        if (t >= st) x += sh[t - st];
        __syncthreads();
        sh[t] = x;
        __syncthreads();
    }
    ps[t + 1] = sh[t];
    if (t == 0) ps[0] = 0;
    __syncthreads();
    const uint32_t total = ps[256];
    const uint32_t gbase = ws[GSOFF + id];     // from scan_groups (exclusive)

    // row r of this group -> binary search word, branchless k-th-set-bit
    for (uint32_t r = t; r < total; r += 256) {
        int lo = 0, hi = 255;
#pragma unroll
        for (int step = 0; step < 8; ++step) {
            const int mid = (lo + hi + 1) >> 1;
            if (ps[mid] <= r) lo = mid; else hi = mid - 1;
        }
        const int w = lo;
        uint32_t k = r - ps[w];
        uint32_t m = wds[w];
        int p = 0;
#pragma unroll
        for (int shw = 16; shw >= 1; shw >>= 1) {
            const uint32_t lowmask = (1u << shw) - 1u;
            const uint32_t c = __popc(m & lowmask);
            const bool go = (k >= c);
            k -= go ? c : 0u;
            m = go ? (m >> shw) : (m & lowmask);
            p += go ? shw : 0;
        }
        const int inbit = ((g * 256 + w) << 5) + p;
        const int c1 = inbit / R;
        const int c2 = inbit - c1 * R;
        out4[gbase + r] = make_int4(B - s, c1 - s, c2 - s, 0);
    }
}

// ================= fallback path (small ws): global-atomic mark ==========
__global__ void zero_ws_kernel(uint32_t* __restrict__ ws, int nwords) {
    int i = blockIdx.x * blockDim.x + threadIdx.x;
    if (i < nwords) ws[i] = 0u;
}

__global__ void mark_global_kernel(const int4* __restrict__ coords,
                                   const int* __restrict__ dstride,
                                   uint32_t* __restrict__ bitmap, int n) {
    int i = blockIdx.x * blockDim.x + threadIdx.x;
    if (i >= n) return;
    const int s = dstride[0];
    const int R = 256 + 2 * s;
    const int W = (R * R + 31) >> 5;
    const int4 c = coords[i];
#pragma unroll
    for (int iz = 0; iz < 3; ++iz) {
        uint32_t* sl = bitmap + (size_t)(c.x + iz * s) * W;
#pragma unroll
        for (int iy = 0; iy < 3; ++iy) {
            const int b0 = (c.y + iy * s) * R + c.z;
            const int w0 = b0 >> 5, off = b0 & 31;
            if (off + 2 * s < 32) {
                atomicOr(sl + w0, (1u << off) | (1u << (off + s)) | (1u << (off + 2 * s)));
            } else {
#pragma unroll
                for (int ix = 0; ix < 3; ++ix) {
                    const int bb = b0 + ix * s;
                    atomicOr(sl + (bb >> 5), 1u << (bb & 31));
                }
            }
        }
    }
}

__global__ void block_sums_kernel(uint32_t* __restrict__ ws) {
    __shared__ uint32_t red[256];
    const uint32_t* bitmap = ws + BMOFF;
    uint32_t* bs = ws + BSOFF;
    const int b = blockIdx.x, t = threadIdx.x;
    const int w = b * WPB + t * 4;
    uint32_t s = 0;
    if (w + 3 < MAXWORDS) {
        const uint4 v = *reinterpret_cast<const uint4*>(bitmap + w);
        s = __popc(v.x) + __popc(v.y) + __popc(v.z) + __popc(v.w);
    } else {
#pragma unroll
        for (int j = 0; j < 4; ++j)
            if (w + j < MAXWORDS) s += __popc(bitmap[w + j]);
    }
    red[t] = s;
    __syncthreads();
    for (int st = 128; st > 0; st >>= 1) {
        if (t < st) red[t] += red[t + st];
        __syncthreads();
    }
    if (t == 0) bs[b] = red[0];
}

__global__ void scan_sums_kernel(uint32_t* __restrict__ ws) {
    __shared__ uint32_t sh[1024];
    const int t = threadIdx.x;
    uint32_t* bs = ws + BSOFF;
    const uint32_t v = (t < NBSCAN) ? bs[t] : 0u;
    sh[t] = v;
    __syncthreads();
    for (int st = 1; st < 1024; st <<= 1) {
        uint32_t x = sh[t];
        if (t >= st) x += sh[t - st];
        __syncthreads();
        sh[t] = x;
        __syncthreads();
    }
    if (t < NBSCAN) bs[t] = sh[t] - v;
    if (t == 0) ws[CNT] = sh[1023];
}

__global__ void fill_tail_gs_kernel(int4* __restrict__ out, const uint32_t* __restrict__ ws, int n4) {
    const uint32_t cnt = ws[CNT];
    const uint32_t stride = gridDim.x * 256u;
    const int4 f = make_int4(FILLV, FILLV, FILLV, FILLV);
    for (uint32_t i = cnt + blockIdx.x * 256u + threadIdx.x; i < (uint32_t)n4; i += stride)
        out[i] = f;
}

__global__ void scatter_fb_kernel(const uint32_t* __restrict__ ws, const int* __restrict__ dstride,
                                  int* __restrict__ out) {
    __shared__ uint32_t sh[256];
    const uint32_t* bitmap = ws + BMOFF;
    const uint32_t* boffs = ws + BSOFF;
    const int b = blockIdx.x, t = threadIdx.x;
    const int s = dstride[0];
    const int R = 256 + 2 * s;
    const int W = (R * R + 31) >> 5;
    const int w = b * WPB + t * 4;
    uint32_t wd[4] = {0u, 0u, 0u, 0u};
    if (w + 3 < MAXWORDS) {
        const uint4 v = *reinterpret_cast<const uint4*>(bitmap + w);
        wd[0] = v.x; wd[1] = v.y; wd[2] = v.z; wd[3] = v.w;
    } else {
#pragma unroll
        for (int j = 0; j < 4; ++j)
            if (w + j < MAXWORDS) wd[j] = bitmap[w + j];
    }
    const uint32_t cnt = __popc(wd[0]) + __popc(wd[1]) + __popc(wd[2]) + __popc(wd[3]);
    sh[t] = cnt;
    __syncthreads();
    for (int st = 1; st < 256; st <<= 1) {
        uint32_t x = sh[t];
        if (t >= st) x += sh[t - st];
        __syncthreads();
        sh[t] = x;
        __syncthreads();
    }
    uint32_t pos = boffs[b] + sh[t] - cnt;
    int4* out4 = reinterpret_cast<int4*>(out);
#pragma unroll
    for (int j = 0; j < 4; ++j) {
        uint32_t m = wd[j];
        if (!m) continue;
        const int wi = w + j;
        const int slice = wi / W;
        const int base = (wi - slice * W) * 32;
        while (m) {
            const int bit = __ffs(m) - 1;
            m &= m - 1;
            const int inbit = base + bit;
            const int c1i = inbit / R;
            const int c2i = inbit - c1i * R;
            out4[pos++] = make_int4(slice - s, c1i - s, c2i - s, 0);
        }
    }
}

extern "C" void kernel_launch(void* const* d_in, const int* in_sizes, int n_in,
                              void* d_out, int out_size, void* d_ws, size_t ws_size,
                              hipStream_t stream) {
    const int4* coords = (const int4*)d_in[0];
    const int* dstride = (const int*)d_in[1];
    int* out = (int*)d_out;
    uint32_t* ws = (uint32_t*)d_ws;
    const int n = in_sizes[0] / 4;      // 500,000 coords
    const int rows4 = out_size / 4;     // 13,500,000 output rows

    const size_t need_fast = ((size_t)EOFF + (size_t)(n + 1) / 2) * 4;  // ~3.8 MB
    const bool fast = ws_size >= need_fast;

    if (fast) {
        hipLaunchKernelGGL(hist_kernel, dim3(SORTB), dim3(256), 0, stream, coords, ws, n);
        hipLaunchKernelGGL(scan_off_kernel, dim3(1), dim3(256), 0, stream, ws);
        hipLaunchKernelGGL(sort_kernel, dim3(SORTB), dim3(256), 0, stream, coords, ws, n);
        hipLaunchKernelGGL(mark_lds_kernel, dim3(MAXSLICES), dim3(1024), 0, stream, ws, dstride);
        hipLaunchKernelGGL(scan_groups_kernel, dim3(1), dim3(1024), 0, stream, ws, dstride);
        hipLaunchKernelGGL(scatter_fill_kernel, dim3(SCGRID), dim3(256), 0, stream,
                           ws, dstride, out, rows4);
    } else {
        const int zeroN = BMOFF + MAXWORDS;
        hipLaunchKernelGGL(zero_ws_kernel, dim3((zeroN + 255) / 256), dim3(256), 0, stream, ws, zeroN);
        hipLaunchKernelGGL(mark_global_kernel, dim3((n + 255) / 256), dim3(256), 0, stream,
                           coords, dstride, ws + BMOFF, n);
        hipLaunchKernelGGL(block_sums_kernel, dim3(NBSCAN), dim3(256), 0, stream, ws);
        hipLaunchKernelGGL(scan_sums_kernel, dim3(1), dim3(1024), 0, stream, ws);
        hipLaunchKernelGGL(fill_tail_gs_kernel, dim3(1024), dim3(256), 0, stream,
                           (int4*)out, ws, rows4);
        hipLaunchKernelGGL(scatter_fb_kernel, dim3(NBSCAN), dim3(256), 0, stream, ws, dstride, out);
    }
}

// Round 9
// 70.746 us; speedup vs baseline: 1.4475x; 1.0542x over previous
//
#include <hip/hip_runtime.h>
#include <stdint.h>

// CoordinateDensification: neighbor-expand (27 offsets, stride*[-1,0,1]^3) then
// unique rows sorted lexicographically, padded with INT32_MAX to N*27 rows.
//
// Bitmap layout (slice-major, lexicographic): slice B = biased c0' in [0, R),
// within-slice bit = c1'*R + c2', word = B*W + bit/32, W = ceil(R*R/32).
//
// Fast path, 4 launches (r8 proven structure, serial 1-block kernels folded
// into their consumers via cheap redundant recompute):
//   1. hist        : per-block c0 histograms (LDS atomics)
//   2. sort        : each block re-scans the hist table itself (no scan_off
//                    launch), then counting-sorts -> packed (c1,c2) entries;
//                    block 0 writes class starts CS for mark.
//   3. mark_lds    : per-slice LDS bitmap + flush + group popcount sums
//   4. scatter_fill: each block reduces gs[0..id) for its base (L2-hot, no
//                    scan_groups launch), prefix-scans popcounts in LDS, then
//                    emits row r via binary-search + branchless k-th-set-bit
//                    -> wave-contiguous plain int4 stores; spare blocks
//                    reduce all gs for cnt and fill the tail with INT32_MAX.
// Fallback (small ws): round-1-style global-atomic mark pipeline.

static constexpr int MAXSTRIDE  = 8;
static constexpr int MAXR       = 256 + 2 * MAXSTRIDE;      // 272
static constexpr int MAXSLICES  = MAXR;                     // 272
static constexpr int MAXW       = (MAXR * MAXR + 31) / 32;  // 2312 words/slice
static constexpr int MAXGPS     = (MAXW + 255) / 256;       // 10 groups/slice
static constexpr int MAXWORDS   = MAXSLICES * MAXW;         // 628,864 words
static constexpr int FILLV      = 0x7FFFFFFF;
static constexpr int SORTB      = 128;
static constexpr int FILLBLOCKS = 1024;
static constexpr int SCGRID     = MAXSLICES * MAXGPS + FILLBLOCKS;  // 3744
// fallback scan geometry
static constexpr int WPB        = 1024;
static constexpr int NBSCAN     = (MAXWORDS + WPB - 1) / WPB;       // 615

// ws layout (uint32_t words):
static constexpr int CNT   = 0;                      // unique count (fallback)
static constexpr int BSOFF = 16;                     // fallback block sums [615]
static constexpr int GSOFF = 1024;                   // group sums [<=2720]
static constexpr int BMOFF = 4096;                   // bitmap [MAXWORDS]
static constexpr int HOFF  = BMOFF + MAXWORDS;       // hist SORTBx256
static constexpr int OOFF  = HOFF + SORTB * 256;     // (unused in fast path)
static constexpr int CSOFF = OOFF + SORTB * 256;     // class starts [257]
static constexpr int EOFF  = CSOFF + 512;            // packed entries (ushort)

// ---------------- 1. hist ------------------------------------------------
__global__ void hist_kernel(const int4* __restrict__ coords, uint32_t* __restrict__ ws, int n) {
    __shared__ uint32_t h[256];
    const int t = threadIdx.x, b = blockIdx.x;
    h[t] = 0;
    __syncthreads();
    const int chunk = (n + gridDim.x - 1) / gridDim.x;
    const int start = b * chunk;
    const int end = min(n, start + chunk);
    for (int i = start + t; i < end; i += 256)
        atomicAdd(&h[coords[i].x], 1u);
    __syncthreads();
    ws[HOFF + b * 256 + t] = h[t];
}

// ---------------- 2. sort (self-scan, no scan_off launch) ----------------
__global__ void sort_kernel(const int4* __restrict__ coords, uint32_t* __restrict__ ws, int n) {
    __shared__ uint32_t sh[256];
    __shared__ uint32_t cnt[256];
    __shared__ uint32_t obase[256];
    const int t = threadIdx.x, b = blockIdx.x;
    const uint32_t* H = ws + HOFF;

    // column-c walk over all block histograms: run_b = sum_{bb<b} H[bb][c],
    // tot = total count of class c. Coalesced (consecutive c per bb).
    uint32_t run_b = 0, tot = 0;
    for (int bb = 0; bb < SORTB; ++bb) {
        const uint32_t h = H[bb * 256 + t];
        if (bb == b) run_b = tot;
        tot += h;
    }
    // block-scan tot -> exclusive class start CS[c]
    sh[t] = tot;
    __syncthreads();
    for (int st = 1; st < 256; st <<= 1) {
        uint32_t x = sh[t];
        if (t >= st) x += sh[t - st];
        __syncthreads();
        sh[t] = x;
        __syncthreads();
    }
    const uint32_t cs = sh[t] - tot;          // exclusive class start
    if (b == 0) {
        ws[CSOFF + t] = cs;
        if (t == 255) ws[CSOFF + 256] = sh[255];
    }
    cnt[t] = 0;
    obase[t] = cs + run_b;
    __syncthreads();

    uint16_t* entries = (uint16_t*)(ws + EOFF);
    const int chunk = (n + gridDim.x - 1) / gridDim.x;
    const int start = b * chunk;
    const int end = min(n, start + chunk);
    for (int i = start + t; i < end; i += 256) {
        const int4 c = coords[i];
        const uint32_t r = atomicAdd(&cnt[c.x], 1u);
        entries[obase[c.x] + r] = (uint16_t)((c.y << 8) | c.z);
    }
}

// ---------------- 3. mark: LDS bitmap + flush + group sums ---------------
__global__ __launch_bounds__(1024) void mark_lds_kernel(uint32_t* __restrict__ ws,
                                                        const int* __restrict__ dstride) {
    __shared__ uint32_t bm[MAXW];
    const int B = blockIdx.x, t = threadIdx.x;
    const int s = dstride[0];
    const int R = 256 + 2 * s;
    const int W = (R * R + 31) >> 5;
    const int GPS = (W + 255) >> 8;
    if (B >= R) return;                       // uniform per block
    for (int w = t; w < MAXW; w += 1024) bm[w] = 0;
    __syncthreads();
    const uint32_t* CS = ws + CSOFF;
    const uint16_t* entries = (const uint16_t*)(ws + EOFF);
#pragma unroll
    for (int k = 0; k < 3; ++k) {
        const int c0 = B - k * s;             // class whose iz=k neighbor is slice B
        if (c0 < 0 || c0 > 255) continue;
        const uint32_t st = CS[c0], en = CS[c0 + 1];
        for (uint32_t i = st + t; i < en; i += 1024) {
            const uint32_t e = entries[i];
            const int c1 = e >> 8, c2 = e & 255;
#pragma unroll
            for (int iy = 0; iy < 3; ++iy) {
                const int b0 = (c1 + iy * s) * R + c2;   // ix = 0 (biased)
                const int w0 = b0 >> 5, off = b0 & 31;
                if (off + 2 * s < 32) {
                    atomicOr(&bm[w0], (1u << off) | (1u << (off + s)) | (1u << (off + 2 * s)));
                } else {
#pragma unroll
                    for (int ix = 0; ix < 3; ++ix) {
                        const int bb = b0 + ix * s;
                        atomicOr(&bm[bb >> 5], 1u << (bb & 31));
                    }
                }
            }
        }
    }
    __syncthreads();
    // flush: every word written (zeros included) -> no global pre-zero needed
    uint32_t* g = ws + BMOFF + (size_t)B * W;
    for (int w = t; w < W; w += 1024) g[w] = bm[w];
    // group sums: wave wv handles words [wv*256, wv*256+256) of this slice
    const int wv = t >> 6, ln = t & 63;
    if (wv < GPS) {
        uint32_t s4 = 0;
        const int w0 = wv * 256 + ln * 4;
#pragma unroll
        for (int j = 0; j < 4; ++j)
            if (w0 + j < W) s4 += __popc(bm[w0 + j]);
#pragma unroll
        for (int off = 32; off > 0; off >>= 1) s4 += __shfl_down(s4, off);
        if (ln == 0) ws[GSOFF + B * GPS + wv] = s4;
    }
}

// ---------------- 4. scatter + tail fill (self gs-reduction) -------------
__global__ __launch_bounds__(256) void scatter_fill_kernel(const uint32_t* __restrict__ ws,
                                                           const int* __restrict__ dstride,
                                                           int* __restrict__ out, int n4) {
    const int s = dstride[0];
    const int R = 256 + 2 * s;
    const int W = (R * R + 31) >> 5;
    const int GPS = (W + 255) >> 8;
    const int NG = R * GPS;
    const int id = blockIdx.x, t = threadIdx.x;
    const uint32_t* gs = ws + GSOFF;
    int4* out4 = reinterpret_cast<int4*>(out);

    __shared__ uint32_t sh[256];
    __shared__ uint32_t ps[257];
    __shared__ uint32_t wds[256];

    if (id >= NG) {                            // tail-fill role (block-uniform)
        uint32_t acc = 0;
        for (int j = t; j < NG; j += 256) acc += gs[j];
        sh[t] = acc;
        __syncthreads();
        for (int st = 128; st > 0; st >>= 1) {
            if (t < st) sh[t] += sh[t + st];
            __syncthreads();
        }
        const uint32_t cnt = sh[0];            // total unique rows
        const uint32_t fb = (uint32_t)(id - NG);
        const uint32_t FB = (uint32_t)(gridDim.x - NG);
        const int4 f = make_int4(FILLV, FILLV, FILLV, FILLV);
        for (uint32_t i = cnt + fb * 256u + (uint32_t)t; i < (uint32_t)n4; i += FB * 256u)
            out4[i] = f;
        return;
    }

    const int B = id / GPS;
    const int g = id - B * GPS;
    const int widx = g * 256 + t;              // word within slice
    const uint32_t wd = (widx < W) ? ws[BMOFF + (size_t)B * W + widx] : 0u;
    wds[t] = wd;
    const uint32_t pc = __popc(wd);

    // block output base = sum of gs[0..id)  (tiny, L2-hot)
    uint32_t acc = 0;
    for (int j = t; j < id; j += 256) acc += gs[j];
    sh[t] = acc;
    __syncthreads();
    for (int st = 128; st > 0; st >>= 1) {
        if (t < st) sh[t] += sh[t + st];
        __syncthreads();
    }
    const uint32_t gbase = sh[0];
    __syncthreads();

    // inclusive scan of popcounts -> ps[] (ps[w] = exclusive prefix at word w)
    sh[t] = pc;
    __syncthreads();
    for (int st = 1; st < 256; st <<= 1) {
        uint32_t x = sh[t];
        if (t >= st) x += sh[t - st];
        __syncthreads();
        sh[t] = x;
        __syncthreads();
    }
    ps[t + 1] = sh[t];
    if (t == 0) ps[0] = 0;
    __syncthreads();
    const uint32_t total = ps[256];

    // row r of this group -> binary search word, branchless k-th-set-bit
    for (uint32_t r = t; r < total; r += 256) {
        int lo = 0, hi = 255;
#pragma unroll
        for (int step = 0; step < 8; ++step) {
            const int mid = (lo + hi + 1) >> 1;
            if (ps[mid] <= r) lo = mid; else hi = mid - 1;
        }
        const int w = lo;
        uint32_t k = r - ps[w];
        uint32_t m = wds[w];
        int p = 0;
#pragma unroll
        for (int shw = 16; shw >= 1; shw >>= 1) {
            const uint32_t lowmask = (1u << shw) - 1u;
            const uint32_t c = __popc(m & lowmask);
            const bool go = (k >= c);
            k -= go ? c : 0u;
            m = go ? (m >> shw) : (m & lowmask);
            p += go ? shw : 0;
        }
        const int inbit = ((g * 256 + w) << 5) + p;
        const int c1 = inbit / R;
        const int c2 = inbit - c1 * R;
        out4[gbase + r] = make_int4(B - s, c1 - s, c2 - s, 0);
    }
}

// ================= fallback path (small ws): global-atomic mark ==========
__global__ void zero_ws_kernel(uint32_t* __restrict__ ws, int nwords) {
    int i = blockIdx.x * blockDim.x + threadIdx.x;
    if (i < nwords) ws[i] = 0u;
}

__global__ void mark_global_kernel(const int4* __restrict__ coords,
                                   const int* __restrict__ dstride,
                                   uint32_t* __restrict__ bitmap, int n) {
    int i = blockIdx.x * blockDim.x + threadIdx.x;
    if (i >= n) return;
    const int s = dstride[0];
    const int R = 256 + 2 * s;
    const int W = (R * R + 31) >> 5;
    const int4 c = coords[i];
#pragma unroll
    for (int iz = 0; iz < 3; ++iz) {
        uint32_t* sl = bitmap + (size_t)(c.x + iz * s) * W;
#pragma unroll
        for (int iy = 0; iy < 3; ++iy) {
            const int b0 = (c.y + iy * s) * R + c.z;
            const int w0 = b0 >> 5, off = b0 & 31;
            if (off + 2 * s < 32) {
                atomicOr(sl + w0, (1u << off) | (1u << (off + s)) | (1u << (off + 2 * s)));
            } else {
#pragma unroll
                for (int ix = 0; ix < 3; ++ix) {
                    const int bb = b0 + ix * s;
                    atomicOr(sl + (bb >> 5), 1u << (bb & 31));
                }
            }
        }
    }
}

__global__ void block_sums_kernel(uint32_t* __restrict__ ws) {
    __shared__ uint32_t red[256];
    const uint32_t* bitmap = ws + BMOFF;
    uint32_t* bs = ws + BSOFF;
    const int b = blockIdx.x, t = threadIdx.x;
    const int w = b * WPB + t * 4;
    uint32_t s = 0;
    if (w + 3 < MAXWORDS) {
        const uint4 v = *reinterpret_cast<const uint4*>(bitmap + w);
        s = __popc(v.x) + __popc(v.y) + __popc(v.z) + __popc(v.w);
    } else {
#pragma unroll
        for (int j = 0; j < 4; ++j)
            if (w + j < MAXWORDS) s += __popc(bitmap[w + j]);
    }
    red[t] = s;
    __syncthreads();
    for (int st = 128; st > 0; st >>= 1) {
        if (t < st) red[t] += red[t + st];
        __syncthreads();
    }
    if (t == 0) bs[b] = red[0];
}

__global__ void scan_sums_kernel(uint32_t* __restrict__ ws) {
    __shared__ uint32_t sh[1024];
    const int t = threadIdx.x;
    uint32_t* bs = ws + BSOFF;
    const uint32_t v = (t < NBSCAN) ? bs[t] : 0u;
    sh[t] = v;
    __syncthreads();
    for (int st = 1; st < 1024; st <<= 1) {
        uint32_t x = sh[t];
        if (t >= st) x += sh[t - st];
        __syncthreads();
        sh[t] = x;
        __syncthreads();
    }
    if (t < NBSCAN) bs[t] = sh[t] - v;
    if (t == 0) ws[CNT] = sh[1023];
}

__global__ void fill_tail_gs_kernel(int4* __restrict__ out, const uint32_t* __restrict__ ws, int n4) {
    const uint32_t cnt = ws[CNT];
    const uint32_t stride = gridDim.x * 256u;
    const int4 f = make_int4(FILLV, FILLV, FILLV, FILLV);
    for (uint32_t i = cnt + blockIdx.x * 256u + threadIdx.x; i < (uint32_t)n4; i += stride)
        out[i] = f;
}

__global__ void scatter_fb_kernel(const uint32_t* __restrict__ ws, const int* __restrict__ dstride,
                                  int* __restrict__ out) {
    __shared__ uint32_t sh[256];
    const uint32_t* bitmap = ws + BMOFF;
    const uint32_t* boffs = ws + BSOFF;
    const int b = blockIdx.x, t = threadIdx.x;
    const int s = dstride[0];
    const int R = 256 + 2 * s;
    const int W = (R * R + 31) >> 5;
    const int w = b * WPB + t * 4;
    uint32_t wd[4] = {0u, 0u, 0u, 0u};
    if (w + 3 < MAXWORDS) {
        const uint4 v = *reinterpret_cast<const uint4*>(bitmap + w);
        wd[0] = v.x; wd[1] = v.y; wd[2] = v.z; wd[3] = v.w;
    } else {
#pragma unroll
        for (int j = 0; j < 4; ++j)
            if (w + j < MAXWORDS) wd[j] = bitmap[w + j];
    }
    const uint32_t cnt = __popc(wd[0]) + __popc(wd[1]) + __popc(wd[2]) + __popc(wd[3]);
    sh[t] = cnt;
    __syncthreads();
    for (int st = 1; st < 256; st <<= 1) {
        uint32_t x = sh[t];
        if (t >= st) x += sh[t - st];
        __syncthreads();
        sh[t] = x;
        __syncthreads();
    }
    uint32_t pos = boffs[b] + sh[t] - cnt;
    int4* out4 = reinterpret_cast<int4*>(out);
#pragma unroll
    for (int j = 0; j < 4; ++j) {
        uint32_t m = wd[j];
        if (!m) continue;
        const int wi = w + j;
        const int slice = wi / W;
        const int base = (wi - slice * W) * 32;
        while (m) {
            const int bit = __ffs(m) - 1;
            m &= m - 1;
            const int inbit = base + bit;
            const int c1i = inbit / R;
            const int c2i = inbit - c1i * R;
            out4[pos++] = make_int4(slice - s, c1i - s, c2i - s, 0);
        }
    }
}

extern "C" void kernel_launch(void* const* d_in, const int* in_sizes, int n_in,
                              void* d_out, int out_size, void* d_ws, size_t ws_size,
                              hipStream_t stream) {
    const int4* coords = (const int4*)d_in[0];
    const int* dstride = (const int*)d_in[1];
    int* out = (int*)d_out;
    uint32_t* ws = (uint32_t*)d_ws;
    const int n = in_sizes[0] / 4;      // 500,000 coords
    const int rows4 = out_size / 4;     // 13,500,000 output rows

    const size_t need_fast = ((size_t)EOFF + (size_t)(n + 1) / 2) * 4;  // ~3.8 MB
    const bool fast = ws_size >= need_fast;

    if (fast) {
        hipLaunchKernelGGL(hist_kernel, dim3(SORTB), dim3(256), 0, stream, coords, ws, n);
        hipLaunchKernelGGL(sort_kernel, dim3(SORTB), dim3(256), 0, stream, coords, ws, n);
        hipLaunchKernelGGL(mark_lds_kernel, dim3(MAXSLICES), dim3(1024), 0, stream, ws, dstride);
        hipLaunchKernelGGL(scatter_fill_kernel, dim3(SCGRID), dim3(256), 0, stream,
                           ws, dstride, out, rows4);
    } else {
        const int zeroN = BMOFF + MAXWORDS;
        hipLaunchKernelGGL(zero_ws_kernel, dim3((zeroN + 255) / 256), dim3(256), 0, stream, ws, zeroN);
        hipLaunchKernelGGL(mark_global_kernel, dim3((n + 255) / 256), dim3(256), 0, stream,
                           coords, dstride, ws + BMOFF, n);
        hipLaunchKernelGGL(block_sums_kernel, dim3(NBSCAN), dim3(256), 0, stream, ws);
        hipLaunchKernelGGL(scan_sums_kernel, dim3(1), dim3(1024), 0, stream, ws);
        hipLaunchKernelGGL(fill_tail_gs_kernel, dim3(1024), dim3(256), 0, stream,
                           (int4*)out, ws, rows4);
        hipLaunchKernelGGL(scatter_fb_kernel, dim3(NBSCAN), dim3(256), 0, stream, ws, dstride, out);
    }
}